// Round 10
// baseline (293.788 us; speedup 1.0000x reference)
//
#include <hip/hip_runtime.h>
#include <math.h>

#define BQ 16384      // batch
#define KFP 800       // padded quanv feature dim (196*4 = 784, +16 zero pad)
#define NH 256        // hidden dim
#define NCLS 10

typedef float f32x4 __attribute__((ext_vector_type(4)));
typedef unsigned int u32x2 __attribute__((ext_vector_type(2)));
typedef __bf16 bf16x8 __attribute__((ext_vector_type(8)));
typedef __bf16 bf16x4 __attribute__((ext_vector_type(4)));

// ===================== prep: build U + weight cvt + zero stats =============
// Amp index bits: wire w <-> bit (8>>w), matching reference flatten order.
// Lane mapping for quanv: bit5 = w0 amp-bit, bit4 = ReIm.
// Abuf layout: flat f: m=f&7, row=(f>>3)&15, kg=(f>>7)&3, hl=(f>>9)&1, t=f>>10.

template<int ST>
__device__ __forceinline__ void u_ry(float* sr, float* si, float c, float s) {
#pragma unroll
  for (int i = 0; i < 16; i++) {
    if (i & ST) continue;
    const int j = i | ST;
    const float a0r = sr[i], a0i = si[i], a1r = sr[j], a1i = si[j];
    sr[i] = c * a0r - s * a1r;  si[i] = c * a0i - s * a1i;
    sr[j] = s * a0r + c * a1r;  si[j] = s * a0i + c * a1i;
  }
}
template<int ST>
__device__ __forceinline__ void u_rz(float* sr, float* si, float c, float s) {
#pragma unroll
  for (int i = 0; i < 16; i++) {
    const float pz = (i & ST) ? s : -s;
    const float ar = sr[i], ai = si[i];
    sr[i] = c * ar - pz * ai;
    si[i] = c * ai + pz * ar;
  }
}
template<int SC, int STG>
__device__ __forceinline__ void u_cnot(float* sr, float* si) {
#pragma unroll
  for (int i = 0; i < 16; i++) {
    if (!(i & SC) || (i & STG)) continue;
    const int j = i | STG;
    float t;
    t = sr[i]; sr[i] = sr[j]; sr[j] = t;
    t = si[i]; si[i] = si[j]; si[j] = t;
  }
}

__global__ __launch_bounds__(256) void prep_kernel(
    const float* __restrict__ qp, const float* __restrict__ w1,
    const float* __restrict__ w2, __bf16* __restrict__ Abuf,
    __bf16* __restrict__ w1b, __bf16* __restrict__ w2b,
    float* __restrict__ gs1, float* __restrict__ gs2) {
  const int bid = blockIdx.x;
  const int tid = threadIdx.x;
  if (bid == 0) {
    gs1[tid] = 0.f; gs1[256 + tid] = 0.f;
    gs2[tid] = 0.f; gs2[256 + tid] = 0.f;
    __shared__ float Ur[16][16], Ui[16][16];
    if (tid < 16) {
      float sr[16], si[16];
#pragma unroll
      for (int i = 0; i < 16; i++) { sr[i] = (i == tid) ? 1.f : 0.f; si[i] = 0.f; }
#pragma unroll
      for (int l = 0; l < 2; l++) {
        { const float t = qp[l*8 + 0] * 0.5f; u_ry<8>(sr, si, cosf(t), sinf(t)); }
        { const float t = qp[l*8 + 1] * 0.5f; u_rz<8>(sr, si, cosf(t), sinf(t)); }
        { const float t = qp[l*8 + 2] * 0.5f; u_ry<4>(sr, si, cosf(t), sinf(t)); }
        { const float t = qp[l*8 + 3] * 0.5f; u_rz<4>(sr, si, cosf(t), sinf(t)); }
        { const float t = qp[l*8 + 4] * 0.5f; u_ry<2>(sr, si, cosf(t), sinf(t)); }
        { const float t = qp[l*8 + 5] * 0.5f; u_rz<2>(sr, si, cosf(t), sinf(t)); }
        { const float t = qp[l*8 + 6] * 0.5f; u_ry<1>(sr, si, cosf(t), sinf(t)); }
        { const float t = qp[l*8 + 7] * 0.5f; u_rz<1>(sr, si, cosf(t), sinf(t)); }
        u_cnot<8, 4>(sr, si);
        u_cnot<4, 2>(sr, si);
        u_cnot<2, 1>(sr, si);
      }
#pragma unroll
      for (int r = 0; r < 16; r++) { Ur[r][tid] = sr[r]; Ui[r][tid] = si[r]; }
    }
    __syncthreads();
    for (int f = tid; f < 2048; f += 256) {
      const int m   = f & 7;
      const int row = (f >> 3) & 15;
      const int kg  = (f >> 7) & 3;
      const int hl  = (f >> 9) & 1;
      const int t   = (f >> 10) & 1;
      const int k   = kg * 8 + m;
      const int ri_o  = (row >> 2) & 1;
      const int amp_o = ((row >> 3) & 1) * 8 + t * 4 + (row & 3);
      const int ri_i  = (k >> 3) & 1;
      const int amp_i = ((k >> 4) & 1) * 8 + (m >> 2) * 4 + (m & 3);
      const float u_r = Ur[amp_o][amp_i], u_i = Ui[amp_o][amp_i];
      float v = (ri_o == 0) ? ((ri_i == 0) ? u_r : -u_i)
                            : ((ri_i == 0) ? u_i : u_r);
      if (hl) {
        const __bf16 hb = (__bf16)v;
        v = v - (float)hb;
      }
      Abuf[f] = (__bf16)v;
    }
  } else if (bid <= 256) {
    const int r = bid - 1;
    for (int c = tid; c < KFP; c += 256)
      w1b[r * KFP + c] = (c < 784) ? (__bf16)w1[r * 784 + c] : (__bf16)0.f;
  } else {
    const int base = (bid - 257) * 2048 + tid * 8;
    const float4 v0 = *(const float4*)(w2 + base);
    const float4 v1 = *(const float4*)(w2 + base + 4);
    bf16x8 o = {(__bf16)v0.x, (__bf16)v0.y, (__bf16)v0.z, (__bf16)v0.w,
                (__bf16)v1.x, (__bf16)v1.y, (__bf16)v1.z, (__bf16)v1.w};
    *(bf16x8*)(w2b + base) = o;
  }
}

// ======================= quanv via MFMA (2-group ILP) ======================
// One wave carries TWO independent 16-element groups (A: cols 0..15, B:
// +16 batch offset) sharing the same U fragments. The two dependency chains
// interleave, filling the stalls that pinned the 1-group version at ~60%
// VALUBusy with 1 wave/SIMD. Math per element identical to round 9.

__device__ __forceinline__ float swz16(float v) {
  return __int_as_float(__builtin_amdgcn_ds_swizzle(__float_as_int(v), 0x401F));
}
// sum over lane-bit5 pairs: commutative-safe under either swap semantic
__device__ __forceinline__ float plsum(float v) {
  const u32x2 r = __builtin_amdgcn_permlane32_swap(
      __float_as_uint(v), __float_as_uint(v), false, false);
  return __uint_as_float(r.x) + __uint_as_float(r.y);
}
__device__ __forceinline__ float plpick(float v, bool r0sel) {
  const u32x2 r = __builtin_amdgcn_permlane32_swap(
      __float_as_uint(v), __float_as_uint(v), false, false);
  return __uint_as_float(r0sel ? r.x : r.y);
}

struct QGrp {
  f32x4 c0, c1;                  // state (2 MFMA acc chains)
  float ts0, tw1, tw2, tw3, gsc; // current-patch params (tan form)
  float2 t0, t1;                 // NEXT patch's raw values
  const float* xb;
  __bf16* fb;
};

__device__ __forceinline__ void q_trig(QGrp& g, float2 a, float2 b2, float sg0) {
  const float h0 = a.x * 0.5f, h1 = a.y * 0.5f;
  const float h2 = b2.x * 0.5f, h3 = b2.y * 0.5f;
  const float c0_ = __cosf(h0), s0_ = __sinf(h0);
  const float c1_ = __cosf(h1), s1_ = __sinf(h1);
  const float c2_ = __cosf(h2), s2_ = __sinf(h2);
  const float c3_ = __cosf(h3), s3_ = __sinf(h3);
  g.ts0 = sg0 * __fdividef(s0_, c0_);   // angles in [0,0.5] rad, cos>=0.878
  g.tw1 = __fdividef(s1_, c1_);
  g.tw2 = __fdividef(s2_, c2_);
  g.tw3 = __fdividef(s3_, c3_);
  g.gsc = (c0_ * c1_) * (c2_ * c3_);
}

__device__ __forceinline__ void q_meas(const QGrp& g, __bf16* dst,
                                       float sg0, int kg) {
  const f32x4 c0 = g.c0, c1 = g.c1;
  const float sq0 = c0.x * c0.x, sq1 = c0.y * c0.y;
  const float sq2 = c0.z * c0.z, sq3 = c0.w * c0.w;
  const float sq4 = c1.x * c1.x, sq5 = c1.y * c1.y;
  const float sq6 = c1.z * c1.z, sq7 = c1.w * c1.w;
  const float s01 = sq0 + sq1, s23 = sq2 + sq3;
  const float s45 = sq4 + sq5, s67 = sq6 + sq7;
  const float d01 = sq0 - sq1, d23 = sq2 - sq3;
  const float d45 = sq4 - sq5, d67 = sq6 - sq7;
  const float z3 = (d01 + d23) + (d45 + d67);   // sign by w3
  const float z2 = (s01 - s23) + (s45 - s67);   // sign by w2
  const float q03 = s01 + s23, q47 = s45 + s67;
  const float z1 = q03 - q47;                   // sign by w1 (chain)
  const float T  = q03 + q47;
  const float z3a = z3 + swz16(z3);             // ReIm combine (bit4)
  const float z2a = z2 + swz16(z2);
  const float z1a = z1 + swz16(z1);
  // weight by -sg0 BEFORE pair sum: z0 = Ta(bit clear) - Ta(bit set)
  const float Ta  = -sg0 * (T + swz16(T));
  const float z3f = plsum(z3a);                 // w0 combine (bit5)
  const float z2f = plsum(z2a);
  const float z1f = plsum(z1a);
  const float z0f = plsum(Ta);
  if (kg == 0) {
    bf16x4 o = {(__bf16)z0f, (__bf16)z1f, (__bf16)z2f, (__bf16)z3f};
    *(bf16x4*)dst = o;
  }
}

__device__ __forceinline__ void q_step(QGrp& g, bool p32r0,
                                       bf16x8 A0h, bf16x8 A0l,
                                       bf16x8 A1h, bf16x8 A1l) {
  const f32x4 z4 = {0.f, 0.f, 0.f, 0.f};
  float S[8] = {g.c0.x, g.c0.y, g.c0.z, g.c0.w,
                g.c1.x, g.c1.y, g.c1.z, g.c1.w};
  // wire1: pairs (j, j+4)
#pragma unroll
  for (int j = 0; j < 4; j++) {
    const float a = S[j];
    S[j]     = fmaf(-g.tw1, S[4 + j], S[j]);
    S[4 + j] = fmaf( g.tw1, a,        S[4 + j]);
  }
  // wire2: pairs (i, i^2)
#pragma unroll
  for (int base = 0; base < 8; base += 4)
#pragma unroll
    for (int j = 0; j < 2; j++) {
      const int i0 = base + j, i1 = base + j + 2;
      const float a = S[i0];
      S[i0] = fmaf(-g.tw2, S[i1], S[i0]);
      S[i1] = fmaf( g.tw2, a,     S[i1]);
    }
  // wire3: pairs (i, i^1)
#pragma unroll
  for (int i0 = 0; i0 < 8; i0 += 2) {
    const float a = S[i0];
    S[i0]     = fmaf(-g.tw3, S[i0 + 1], S[i0]);
    S[i0 + 1] = fmaf( g.tw3, a,         S[i0 + 1]);
  }
  // wire0: cross-lane bit5 via permlane32 (VALU)
#pragma unroll
  for (int i = 0; i < 8; i++) {
    const float P = plpick(S[i], p32r0);
    S[i] = fmaf(g.ts0, P, S[i]);
  }
  // deferred cos-product scale + hi/lo split
  bf16x8 Bh, Bl;
#pragma unroll
  for (int i = 0; i < 8; i++) {
    const float GS = g.gsc * S[i];
    const __bf16 hb = (__bf16)GS;
    Bh[i] = hb;
    Bl[i] = (__bf16)(GS - (float)hb);
  }
  // 6 MFMAs, two independent depth-2 chains per output
  f32x4 p0 = __builtin_amdgcn_mfma_f32_16x16x32_bf16(A0h, Bh, z4, 0, 0, 0);
  f32x4 q0 = __builtin_amdgcn_mfma_f32_16x16x32_bf16(A0l, Bh, z4, 0, 0, 0);
  q0 = __builtin_amdgcn_mfma_f32_16x16x32_bf16(A0h, Bl, q0, 0, 0, 0);
  f32x4 p1 = __builtin_amdgcn_mfma_f32_16x16x32_bf16(A1h, Bh, z4, 0, 0, 0);
  f32x4 q1 = __builtin_amdgcn_mfma_f32_16x16x32_bf16(A1l, Bh, z4, 0, 0, 0);
  q1 = __builtin_amdgcn_mfma_f32_16x16x32_bf16(A1h, Bl, q1, 0, 0, 0);
  g.c0 = p0 + q0;
  g.c1 = p1 + q1;
}

__global__ __launch_bounds__(64) void quanv_mfma(
    const float* __restrict__ x, const __bf16* __restrict__ Abuf,
    __bf16* __restrict__ feats) {
  const int l = threadIdx.x;              // one wave per block
  const int col = l & 15;
  const int kg = l >> 4;
  const int bA = blockIdx.x * 32 + col;   // group A element
  const int bB = bA + 16;                 // group B element
  const float sg0 = (l & 32) ? 1.f : -1.f;

  // permlane32 partner-selection mask (robust to operand-swap semantics)
  const u32x2 pt = __builtin_amdgcn_permlane32_swap((unsigned)l, (unsigned)l,
                                                    false, false);
  const bool p32r0 = (pt.x == (unsigned)(l ^ 32));

  // shared A fragments (U is the same for both groups)
  const bf16x8* Ab = (const bf16x8*)Abuf;
  const bf16x8 A0h = Ab[(0 * 4 + kg) * 16 + col];
  const bf16x8 A0l = Ab[(1 * 4 + kg) * 16 + col];
  const bf16x8 A1h = Ab[(2 * 4 + kg) * 16 + col];
  const bf16x8 A1l = Ab[(3 * 4 + kg) * 16 + col];

  QGrp A, B;
  A.xb = x + (size_t)bA * 784;  A.fb = feats + (size_t)bA * KFP;
  B.xb = x + (size_t)bB * 784;  B.fb = feats + (size_t)bB * KFP;
  A.c0 = (f32x4){(kg == 0) ? 1.f : 0.f, 0.f, 0.f, 0.f};
  A.c1 = (f32x4){0.f, 0.f, 0.f, 0.f};
  B.c0 = A.c0; B.c1 = A.c1;

  // ---- pipeline prologue: params(p0); step(p0); params(p1); ----
  {
    const float2 a0 = *(const float2*)(A.xb);
    const float2 a1 = *(const float2*)(A.xb + 28);
    const float2 b0 = *(const float2*)(B.xb);
    const float2 b1 = *(const float2*)(B.xb + 28);
    q_trig(A, a0, a1, sg0);
    q_trig(B, b0, b1, sg0);
  }
  A.t0 = *(const float2*)(A.xb + 2);  A.t1 = *(const float2*)(A.xb + 30);
  B.t0 = *(const float2*)(B.xb + 2);  B.t1 = *(const float2*)(B.xb + 30);
  q_step(A, p32r0, A0h, A0l, A1h, A1l);
  q_step(B, p32r0, A0h, A0l, A1h, A1l);
  q_trig(A, A.t0, A.t1, sg0);
  q_trig(B, B.t0, B.t1, sg0);
  A.t0 = *(const float2*)(A.xb + 4);  A.t1 = *(const float2*)(A.xb + 32);
  B.t0 = *(const float2*)(B.xb + 4);  B.t1 = *(const float2*)(B.xb + 32);
  int nrr = 0, ncc = 3;               // next load = patch 3
  __bf16* fpA = A.fb;
  __bf16* fpB = B.fb;

  for (int it = 1; it < 196; ++it) {
    const int off = (it < 194) ? (56 * nrr + 2 * ncc) : 0;
    const float2 nA0 = *(const float2*)(A.xb + off);
    const float2 nA1 = *(const float2*)(A.xb + off + 28);
    const float2 nB0 = *(const float2*)(B.xb + off);
    const float2 nB1 = *(const float2*)(B.xb + off + 28);
    ncc++;
    if (ncc == 14) { ncc = 0; nrr++; }

    q_meas(A, fpA, sg0, kg); fpA += 4;  // state after patch it-1
    q_meas(B, fpB, sg0, kg); fpB += 4;
    q_step(A, p32r0, A0h, A0l, A1h, A1l);   // patch it
    q_step(B, p32r0, A0h, A0l, A1h, A1l);
    q_trig(A, A.t0, A.t1, sg0);             // params for patch it+1
    q_trig(B, B.t0, B.t1, sg0);
    A.t0 = nA0; A.t1 = nA1;
    B.t0 = nB0; B.t1 = nB1;
  }
  q_meas(A, fpA, sg0, kg);
  q_meas(B, fpB, sg0, kg);

  // zero the K padding 784..800
  if (kg == 0) {
    *(uint4*)(A.fb + 784) = (uint4){0, 0, 0, 0};
    *(uint4*)(A.fb + 792) = (uint4){0, 0, 0, 0};
    *(uint4*)(B.fb + 784) = (uint4){0, 0, 0, 0};
    *(uint4*)(B.fb + 792) = (uint4){0, 0, 0, 0};
  }
}

// ========== bf16 MFMA NT GEMM: C = A*B^T + bias, fused BN stats ============
// 1D grid + bijective XCD swizzle (nwg = 512, divisible by 8).
#define GBM 128
#define GBN 64
#define GBK 32

__device__ __forceinline__ void gld16(const void* g, void* l) {
  __builtin_amdgcn_global_load_lds(
      (const __attribute__((address_space(1))) unsigned int*)g,
      (__attribute__((address_space(3))) unsigned int*)l, 16, 0, 0);
}

__global__ __launch_bounds__(256) void gemm_bf16_nt(
    const __bf16* __restrict__ A, const __bf16* __restrict__ B,
    const float* __restrict__ bias, float* __restrict__ C,
    int M, int N, int K, float* __restrict__ gstats) {
  __shared__ char lds[24576];
  const int tid = threadIdx.x;
  const int nwg = gridDim.x;
  const int sid = (blockIdx.x & 7) * (nwg >> 3) + (blockIdx.x >> 3);
  const int bm = (sid >> 2) * GBM;      // N/GBN == 4
  const int bn = (sid & 3) * GBN;
  const int NK = K / GBK;
  const size_t lda = (size_t)K * 2;

  const int srow = tid >> 2;
  const int lc16 = tid & 3;
  const int ag0 = lc16 ^ ((srow >> 1) & 3);
  const int ag1 = lc16 ^ (((srow + 64) >> 1) & 3);
  const char* a0p = (const char*)A + (size_t)(bm + srow) * lda + ag0 * 16;
  const char* a1p = (const char*)A + (size_t)(bm + 64 + srow) * lda + ag1 * 16;
  const char* b0p = (const char*)B + (size_t)(bn + srow) * lda + ag0 * 16;

  const int wid = tid >> 6, lane = tid & 63;
  const int wr = wid >> 1, wc = wid & 1;
  const int ln15 = lane & 15, ln4 = lane >> 4;
  int aoff[4], boff[2];
#pragma unroll
  for (int m = 0; m < 4; m++) {
    const int row = wr * 64 + m * 16 + ln15;
    aoff[m] = row * 64 + ((ln4 ^ ((row >> 1) & 3)) * 16);
  }
#pragma unroll
  for (int n = 0; n < 2; n++) {
    const int row = wc * 32 + n * 16 + ln15;
    boff[n] = 16384 + row * 64 + ((ln4 ^ ((row >> 1) & 3)) * 16);
  }

  f32x4 acc[4][2];
#pragma unroll
  for (int m = 0; m < 4; m++)
#pragma unroll
    for (int n = 0; n < 2; n++) acc[m][n] = (f32x4){0.f, 0.f, 0.f, 0.f};

  auto stage = [&](int buf, int kt) {
    const size_t kb = (size_t)kt * GBK * 2;
    char* as = lds + buf * 8192 + tid * 16;
    char* bs = lds + 16384 + buf * 4096 + tid * 16;
    gld16(a0p + kb, as);
    gld16(a1p + kb, as + 4096);
    gld16(b0p + kb, bs);
  };

  stage(0, 0);
  for (int kt = 0; kt < NK; kt++) {
    __syncthreads();
    if (kt + 1 < NK) stage((kt + 1) & 1, kt + 1);
    const int ab = (kt & 1) * 8192, bb = (kt & 1) * 4096;
    bf16x8 af[4], bfr[2];
#pragma unroll
    for (int m = 0; m < 4; m++) af[m] = *(const bf16x8*)(lds + ab + aoff[m]);
#pragma unroll
    for (int n = 0; n < 2; n++) bfr[n] = *(const bf16x8*)(lds + bb + boff[n]);
#pragma unroll
    for (int m = 0; m < 4; m++)
#pragma unroll
      for (int n = 0; n < 2; n++)
        acc[m][n] = __builtin_amdgcn_mfma_f32_16x16x32_bf16(af[m], bfr[n], acc[m][n], 0, 0, 0);
  }

  // epilogue: C write + per-block column stats (sum, sumsq)
  float csum[2], csq[2];
#pragma unroll
  for (int n = 0; n < 2; n++) {
    const int ccol = bn + wc * 32 + n * 16 + ln15;
    const float bv = bias[ccol];
    float s = 0.f, ss = 0.f;
#pragma unroll
    for (int m = 0; m < 4; m++) {
      const int crow = bm + wr * 64 + m * 16 + ln4 * 4;
#pragma unroll
      for (int r = 0; r < 4; r++) {
        const float v = acc[m][n][r] + bv;
        C[(size_t)(crow + r) * N + ccol] = v;
        s += v; ss += v * v;
      }
    }
    csum[n] = s; csq[n] = ss;
  }
  __syncthreads();                       // LDS staging reads done -> reuse
  float* sred = (float*)lds;             // [2 stats][4 wid][4 ln4][32 col]
#pragma unroll
  for (int n = 0; n < 2; n++) {
    const int slot = wid * 128 + ln4 * 32 + n * 16 + ln15;
    sred[slot] = csum[n];
    sred[512 + slot] = csq[n];
  }
  __syncthreads();
  if (tid < 128) {
    const int colb = tid & 63, which = tid >> 6;
    const int wcc = colb >> 5, c31 = colb & 31;
    float a = 0.f;
    const int base = which * 512 + c31;
#pragma unroll
    for (int w2_ = 0; w2_ < 2; w2_++)
#pragma unroll
      for (int l4 = 0; l4 < 4; l4++)
        a += sred[base + (w2_ * 2 + wcc) * 128 + l4 * 32];
    atomicAdd(&gstats[(bn + colb) * 2 + which], a);
  }
}

// ======================= BN finalize (from fused stats) ====================
__global__ __launch_bounds__(256) void bn_finalize_g(
    const float* __restrict__ gstats, const float* __restrict__ g,
    const float* __restrict__ be, float* __restrict__ ab, float* __restrict__ cb) {
  const int t = threadIdx.x;
  const float s = gstats[t * 2], ss = gstats[t * 2 + 1];
  const float mean = s * (1.f / 16384.f);
  const float var = ss * (1.f / 16384.f) - mean * mean;
  const float rstd = rsqrtf(var + 1e-5f);
  const float a = g[t] * rstd;
  ab[t] = a;
  cb[t] = be[t] - mean * a;
}

// BN+ReLU -> bf16 only (GEMM2 input + residual source)
__global__ __launch_bounds__(256) void bn_relu_cvt(
    const float* __restrict__ h, __bf16* __restrict__ hb,
    const float* __restrict__ ab, const float* __restrict__ cb) {
  const size_t i = (size_t)blockIdx.x * 256 + threadIdx.x;  // float4 index
  const float4 v = ((const float4*)h)[i];
  const int col = (int)((i * 4) & (NH - 1));
  const float4 a = *(const float4*)(ab + col);
  const float4 c = *(const float4*)(cb + col);
  bf16x4 o = {(__bf16)fmaxf(fmaf(v.x, a.x, c.x), 0.f),
              (__bf16)fmaxf(fmaf(v.y, a.y, c.y), 0.f),
              (__bf16)fmaxf(fmaf(v.z, a.z, c.z), 0.f),
              (__bf16)fmaxf(fmaf(v.w, a.w, c.w), 0.f)};
  *(bf16x4*)(hb + i * 4) = o;
}

// ========== fused tail: BN2 + ReLU + residual + head GEMV + log_softmax ====
__global__ __launch_bounds__(256) void tail_fused(
    const float* __restrict__ h2p, const __bf16* __restrict__ h1b,
    const float* __restrict__ ab, const float* __restrict__ cb,
    const float* __restrict__ w3, const float* __restrict__ b3,
    float* __restrict__ out) {
  __shared__ float w3s[NCLS * NH];
  __shared__ float as[NH], cs[NH];
  for (int i = threadIdx.x; i < NCLS * NH; i += 256) w3s[i] = w3[i];
  as[threadIdx.x] = ab[threadIdx.x];
  cs[threadIdx.x] = cb[threadIdx.x];
  __syncthreads();

  const int m = blockIdx.x * 256 + threadIdx.x;
  const float* hr = h2p + (size_t)m * NH;
  const __bf16* rr = h1b + (size_t)m * NH;
  float acc[NCLS];
#pragma unroll
  for (int n = 0; n < NCLS; n++) acc[n] = b3[n];

  for (int k = 0; k < NH; k += 8) {
    const float4 hv0 = *(const float4*)(hr + k);
    const float4 hv1 = *(const float4*)(hr + k + 4);
    const bf16x8 rv = *(const bf16x8*)(rr + k);
    float v[8] = {hv0.x, hv0.y, hv0.z, hv0.w, hv1.x, hv1.y, hv1.z, hv1.w};
#pragma unroll
    for (int j = 0; j < 8; j++)
      v[j] = fmaxf(fmaf(v[j], as[k + j], cs[k + j]), 0.f) + (float)rv[j];
#pragma unroll
    for (int n = 0; n < NCLS; n++) {
      float d = 0.f;
#pragma unroll
      for (int j = 0; j < 8; j++) d = fmaf(v[j], w3s[n * NH + k + j], d);
      acc[n] += d;
    }
  }

  float mx = acc[0];
#pragma unroll
  for (int n = 1; n < NCLS; n++) mx = fmaxf(mx, acc[n]);
  float se = 0.f;
#pragma unroll
  for (int n = 0; n < NCLS; n++) se += expf(acc[n] - mx);
  const float lse = logf(se) + mx;
#pragma unroll
  for (int n = 0; n < NCLS; n++) out[(size_t)m * NCLS + n] = acc[n] - lse;
}

// =========================== launch ========================================
extern "C" void kernel_launch(void* const* d_in, const int* in_sizes, int n_in,
                              void* d_out, int out_size, void* d_ws, size_t ws_size,
                              hipStream_t stream) {
  const float* x   = (const float*)d_in[0];
  const float* qp  = (const float*)d_in[1];
  const float* w1  = (const float*)d_in[2];
  const float* b1  = (const float*)d_in[3];
  const float* g1  = (const float*)d_in[4];
  const float* be1 = (const float*)d_in[5];
  const float* w2  = (const float*)d_in[6];
  const float* b2  = (const float*)d_in[7];
  const float* g2  = (const float*)d_in[8];
  const float* be2 = (const float*)d_in[9];
  const float* w3  = (const float*)d_in[10];
  const float* b3  = (const float*)d_in[11];
  float* out = (float*)d_out;

  char* w = (char*)d_ws;
  __bf16* feats = (__bf16*)w;                         // 26,214,400
  float*  h1    = (float*)(w + 26214400);             // 16,777,216
  float*  h2p   = (float*)(w + 42991616);             // 16,777,216
  __bf16* h1b   = (__bf16*)(w + 59768832);            //  8,388,608
  __bf16* w1b   = (__bf16*)(w + 68157440);            //    409,600
  __bf16* w2b   = (__bf16*)(w + 68567040);            //    131,072
  float*  gs1   = (float*)(w + 68698112);             //      2,048
  float*  gs2   = (float*)(w + 68700160);             //      2,048
  float*  ab1   = (float*)(w + 68702208);
  float*  cb1   = (float*)(w + 68703232);
  float*  ab2   = (float*)(w + 68704256);
  float*  cb2   = (float*)(w + 68705280);
  __bf16* Abuf  = (__bf16*)(w + 68706304);            //      4,096

  prep_kernel<<<289, 256, 0, stream>>>(qp, w1, w2, Abuf, w1b, w2b, gs1, gs2);
  quanv_mfma<<<BQ / 32, 64, 0, stream>>>(x, Abuf, feats);

  gemm_bf16_nt<<<(BQ / GBM) * (NH / GBN), 256, 0, stream>>>(
      feats, w1b, b1, h1, BQ, NH, KFP, gs1);
  bn_finalize_g<<<1, 256, 0, stream>>>(gs1, g1, be1, ab1, cb1);
  bn_relu_cvt<<<(BQ * NH / 4) / 256, 256, 0, stream>>>(h1, h1b, ab1, cb1);

  gemm_bf16_nt<<<(BQ / GBM) * (NH / GBN), 256, 0, stream>>>(
      h1b, w2b, b2, h2p, BQ, NH, NH, gs2);
  bn_finalize_g<<<1, 256, 0, stream>>>(gs2, g2, be2, ab2, cb2);

  tail_fused<<<BQ / 256, 256, 0, stream>>>(h2p, h1b, ab2, cb2, w3, b3, out);
}

// Round 11
// 205.908 us; speedup vs baseline: 1.4268x; 1.4268x over previous
//
#include <hip/hip_runtime.h>
#include <math.h>

#define BQ 16384      // batch
#define KFP 800       // padded quanv feature dim (196*4 = 784, +16 zero pad)
#define NH 256        // hidden dim
#define NCLS 10

typedef float f32x4 __attribute__((ext_vector_type(4)));
typedef unsigned int u32x2 __attribute__((ext_vector_type(2)));
typedef unsigned int u32x4 __attribute__((ext_vector_type(4)));
typedef __bf16 bf16x8 __attribute__((ext_vector_type(8)));
typedef __bf16 bf16x4 __attribute__((ext_vector_type(4)));

// ===================== prep: build U + weight cvt + zero stats =============
// Amp index bits: wire w <-> bit (8>>w), matching reference flatten order.
// Lane mapping for quanv: bit5 = w0 amp-bit, bit4 = ReIm.
// Abuf layout: flat f: m=f&7, row=(f>>3)&15, kg=(f>>7)&3, hl=(f>>9)&1, t=f>>10.

template<int ST>
__device__ __forceinline__ void u_ry(float* sr, float* si, float c, float s) {
#pragma unroll
  for (int i = 0; i < 16; i++) {
    if (i & ST) continue;
    const int j = i | ST;
    const float a0r = sr[i], a0i = si[i], a1r = sr[j], a1i = si[j];
    sr[i] = c * a0r - s * a1r;  si[i] = c * a0i - s * a1i;
    sr[j] = s * a0r + c * a1r;  si[j] = s * a0i + c * a1i;
  }
}
template<int ST>
__device__ __forceinline__ void u_rz(float* sr, float* si, float c, float s) {
#pragma unroll
  for (int i = 0; i < 16; i++) {
    const float pz = (i & ST) ? s : -s;
    const float ar = sr[i], ai = si[i];
    sr[i] = c * ar - pz * ai;
    si[i] = c * ai + pz * ar;
  }
}
template<int SC, int STG>
__device__ __forceinline__ void u_cnot(float* sr, float* si) {
#pragma unroll
  for (int i = 0; i < 16; i++) {
    if (!(i & SC) || (i & STG)) continue;
    const int j = i | STG;
    float t;
    t = sr[i]; sr[i] = sr[j]; sr[j] = t;
    t = si[i]; si[i] = si[j]; si[j] = t;
  }
}

__global__ __launch_bounds__(256) void prep_kernel(
    const float* __restrict__ qp, const float* __restrict__ w1,
    const float* __restrict__ w2, __bf16* __restrict__ Abuf,
    __bf16* __restrict__ w1b, __bf16* __restrict__ w2b,
    float* __restrict__ gs1, float* __restrict__ gs2) {
  const int bid = blockIdx.x;
  const int tid = threadIdx.x;
  if (bid == 0) {
    gs1[tid] = 0.f; gs1[256 + tid] = 0.f;
    gs2[tid] = 0.f; gs2[256 + tid] = 0.f;
    __shared__ float Ur[16][16], Ui[16][16];
    if (tid < 16) {
      float sr[16], si[16];
#pragma unroll
      for (int i = 0; i < 16; i++) { sr[i] = (i == tid) ? 1.f : 0.f; si[i] = 0.f; }
#pragma unroll
      for (int l = 0; l < 2; l++) {
        { const float t = qp[l*8 + 0] * 0.5f; u_ry<8>(sr, si, cosf(t), sinf(t)); }
        { const float t = qp[l*8 + 1] * 0.5f; u_rz<8>(sr, si, cosf(t), sinf(t)); }
        { const float t = qp[l*8 + 2] * 0.5f; u_ry<4>(sr, si, cosf(t), sinf(t)); }
        { const float t = qp[l*8 + 3] * 0.5f; u_rz<4>(sr, si, cosf(t), sinf(t)); }
        { const float t = qp[l*8 + 4] * 0.5f; u_ry<2>(sr, si, cosf(t), sinf(t)); }
        { const float t = qp[l*8 + 5] * 0.5f; u_rz<2>(sr, si, cosf(t), sinf(t)); }
        { const float t = qp[l*8 + 6] * 0.5f; u_ry<1>(sr, si, cosf(t), sinf(t)); }
        { const float t = qp[l*8 + 7] * 0.5f; u_rz<1>(sr, si, cosf(t), sinf(t)); }
        u_cnot<8, 4>(sr, si);
        u_cnot<4, 2>(sr, si);
        u_cnot<2, 1>(sr, si);
      }
#pragma unroll
      for (int r = 0; r < 16; r++) { Ur[r][tid] = sr[r]; Ui[r][tid] = si[r]; }
    }
    __syncthreads();
    for (int f = tid; f < 2048; f += 256) {
      const int m   = f & 7;
      const int row = (f >> 3) & 15;
      const int kg  = (f >> 7) & 3;
      const int hl  = (f >> 9) & 1;
      const int t   = (f >> 10) & 1;
      const int k   = kg * 8 + m;
      const int ri_o  = (row >> 2) & 1;
      const int amp_o = ((row >> 3) & 1) * 8 + t * 4 + (row & 3);
      const int ri_i  = (k >> 3) & 1;
      const int amp_i = ((k >> 4) & 1) * 8 + (m >> 2) * 4 + (m & 3);
      const float u_r = Ur[amp_o][amp_i], u_i = Ui[amp_o][amp_i];
      float v = (ri_o == 0) ? ((ri_i == 0) ? u_r : -u_i)
                            : ((ri_i == 0) ? u_i : u_r);
      if (hl) {
        const __bf16 hb = (__bf16)v;
        v = v - (float)hb;
      }
      Abuf[f] = (__bf16)v;
    }
  } else if (bid <= 256) {
    const int r = bid - 1;
    for (int c = tid; c < KFP; c += 256)
      w1b[r * KFP + c] = (c < 784) ? (__bf16)w1[r * 784 + c] : (__bf16)0.f;
  } else {
    const int base = (bid - 257) * 2048 + tid * 8;
    const float4 v0 = *(const float4*)(w2 + base);
    const float4 v1 = *(const float4*)(w2 + base + 4);
    bf16x8 o = {(__bf16)v0.x, (__bf16)v0.y, (__bf16)v0.z, (__bf16)v0.w,
                (__bf16)v1.x, (__bf16)v1.y, (__bf16)v1.z, (__bf16)v1.w};
    *(bf16x8*)(w2b + base) = o;
  }
}

// ======================= quanv via MFMA (round-9 structure) ================
// 16 elements/wave: col = lane&15, kg = lane>>4; b5 = w0 amp-bit, b4 = ReIm.
// E in tangent form; truncation hi/lo split via v_perm (round-7-verified).
// Measurement deferred one iteration; trig pipelined one iteration ahead.

__device__ __forceinline__ float swz16(float v) {
  return __int_as_float(__builtin_amdgcn_ds_swizzle(__float_as_int(v), 0x401F));
}
// sum over lane-bit5 pairs: commutative-safe under either swap semantic
__device__ __forceinline__ float plsum(float v) {
  const u32x2 r = __builtin_amdgcn_permlane32_swap(
      __float_as_uint(v), __float_as_uint(v), false, false);
  return __uint_as_float(r.x) + __uint_as_float(r.y);
}
__device__ __forceinline__ float plpick(float v, bool r0sel) {
  const u32x2 r = __builtin_amdgcn_permlane32_swap(
      __float_as_uint(v), __float_as_uint(v), false, false);
  return __uint_as_float(r0sel ? r.x : r.y);
}

__global__ __launch_bounds__(256) void quanv_mfma(
    const float* __restrict__ x, const __bf16* __restrict__ Abuf,
    __bf16* __restrict__ feats) {
  const int tid = threadIdx.x;
  const int l = tid & 63;
  const int wv = tid >> 6;
  const int col = l & 15;
  const int kg = l >> 4;
  const int b = blockIdx.x * 64 + wv * 16 + col;
  const float* xb = x + (size_t)b * 784;
  __bf16* fb = feats + (size_t)b * KFP;
  const float sg0 = (l & 32) ? 1.f : -1.f;   // wire0 amp-bit sign (b5)

  // permlane32 partner-selection mask (robust to operand-swap semantics)
  const u32x2 pt = __builtin_amdgcn_permlane32_swap((unsigned)l, (unsigned)l,
                                                    false, false);
  const bool p32r0 = (pt.x == (unsigned)(l ^ 32));

  // A fragments (held in VGPRs for the whole kernel)
  const bf16x8* Ab = (const bf16x8*)Abuf;
  const bf16x8 A0h = Ab[(0 * 4 + kg) * 16 + col];
  const bf16x8 A0l = Ab[(1 * 4 + kg) * 16 + col];
  const bf16x8 A1h = Ab[(2 * 4 + kg) * 16 + col];
  const bf16x8 A1l = Ab[(3 * 4 + kg) * 16 + col];

  f32x4 c0 = {(kg == 0) ? 1.f : 0.f, 0.f, 0.f, 0.f};
  f32x4 c1 = {0.f, 0.f, 0.f, 0.f};
  const f32x4 z4 = {0.f, 0.f, 0.f, 0.f};

  // pipelined per-patch params: tangents (sign-folded for wire0) + cos product
  float ts0, tw1, tw2, tw3, gsc;
  auto trig = [&](float2 a, float2 b2) {
    const float h0 = a.x * 0.5f, h1 = a.y * 0.5f;
    const float h2 = b2.x * 0.5f, h3 = b2.y * 0.5f;
    const float c0_ = __cosf(h0), s0_ = __sinf(h0);
    const float c1_ = __cosf(h1), s1_ = __sinf(h1);
    const float c2_ = __cosf(h2), s2_ = __sinf(h2);
    const float c3_ = __cosf(h3), s3_ = __sinf(h3);
    ts0 = sg0 * __fdividef(s0_, c0_);     // angles in [0,0.5] rad -> cos>=0.878
    tw1 = __fdividef(s1_, c1_);
    tw2 = __fdividef(s2_, c2_);
    tw3 = __fdividef(s3_, c3_);
    gsc = (c0_ * c1_) * (c2_ * c3_);
  };

  // measurement of current state -> store 4 bf16 (lane kg==0)
  auto meas = [&](__bf16* dst) {
    const float sq0 = c0.x * c0.x, sq1 = c0.y * c0.y;
    const float sq2 = c0.z * c0.z, sq3 = c0.w * c0.w;
    const float sq4 = c1.x * c1.x, sq5 = c1.y * c1.y;
    const float sq6 = c1.z * c1.z, sq7 = c1.w * c1.w;
    const float s01 = sq0 + sq1, s23 = sq2 + sq3;
    const float s45 = sq4 + sq5, s67 = sq6 + sq7;
    const float d01 = sq0 - sq1, d23 = sq2 - sq3;
    const float d45 = sq4 - sq5, d67 = sq6 - sq7;
    const float z3 = (d01 + d23) + (d45 + d67);   // sign by w3
    const float z2 = (s01 - s23) + (s45 - s67);   // sign by w2
    const float q03 = s01 + s23, q47 = s45 + s67;
    const float z1 = q03 - q47;                   // sign by w1 (chain)
    const float T  = q03 + q47;
    const float z3a = z3 + swz16(z3);             // ReIm combine (bit4)
    const float z2a = z2 + swz16(z2);
    const float z1a = z1 + swz16(z1);
    // weight by -sg0 BEFORE pair sum: z0 = Ta(bit clear) - Ta(bit set)
    const float Ta  = -sg0 * (T + swz16(T));
    const float z3f = plsum(z3a);                 // w0 combine (bit5)
    const float z2f = plsum(z2a);
    const float z1f = plsum(z1a);
    const float z0f = plsum(Ta);
    if (kg == 0) {
      bf16x4 o = {(__bf16)z0f, (__bf16)z1f, (__bf16)z2f, (__bf16)z3f};
      *(bf16x4*)dst = o;
    }
  };

  // E(vals) in tan form + deferred scale + 6 MFMAs (depth-2 chains)
  auto step = [&]() {
    float S[8] = {c0.x, c0.y, c0.z, c0.w, c1.x, c1.y, c1.z, c1.w};
    // wire1: pairs (j, j+4)
#pragma unroll
    for (int j = 0; j < 4; j++) {
      const float a = S[j];
      S[j]     = fmaf(-tw1, S[4 + j], S[j]);
      S[4 + j] = fmaf( tw1, a,        S[4 + j]);
    }
    // wire2: pairs (i, i^2)
#pragma unroll
    for (int base = 0; base < 8; base += 4)
#pragma unroll
      for (int j = 0; j < 2; j++) {
        const int i0 = base + j, i1 = base + j + 2;
        const float a = S[i0];
        S[i0] = fmaf(-tw2, S[i1], S[i0]);
        S[i1] = fmaf( tw2, a,     S[i1]);
      }
    // wire3: pairs (i, i^1)
#pragma unroll
    for (int i0 = 0; i0 < 8; i0 += 2) {
      const float a = S[i0];
      S[i0]     = fmaf(-tw3, S[i0 + 1], S[i0]);
      S[i0 + 1] = fmaf( tw3, a,         S[i0 + 1]);
    }
    // wire0: cross-lane bit5 via permlane32 (VALU)
#pragma unroll
    for (int i = 0; i < 8; i++) {
      const float P = plpick(S[i], p32r0);
      S[i] = fmaf(ts0, P, S[i]);
    }
    // deferred scale + truncation hi/lo split, packed with v_perm (full-rate
    // bit ops; verified round 7). lo = GS - trunc16(GS), then trunc16(lo).
    unsigned gb[8], lb[8];
#pragma unroll
    for (int i = 0; i < 8; i++) {
      const float GS = gsc * S[i];
      const unsigned bb = __float_as_uint(GS);
      gb[i] = bb;
      lb[i] = __float_as_uint(GS - __uint_as_float(bb & 0xFFFF0000u));
    }
    u32x4 bhv, blv;
#pragma unroll
    for (int j = 0; j < 4; j++) {
      bhv[j] = __builtin_amdgcn_perm(gb[2 * j + 1], gb[2 * j], 0x07060302u);
      blv[j] = __builtin_amdgcn_perm(lb[2 * j + 1], lb[2 * j], 0x07060302u);
    }
    const bf16x8 Bh = __builtin_bit_cast(bf16x8, bhv);
    const bf16x8 Bl = __builtin_bit_cast(bf16x8, blv);
    // 6 MFMAs, two independent depth-2 chains per output
    f32x4 p0 = __builtin_amdgcn_mfma_f32_16x16x32_bf16(A0h, Bh, z4, 0, 0, 0);
    f32x4 q0 = __builtin_amdgcn_mfma_f32_16x16x32_bf16(A0l, Bh, z4, 0, 0, 0);
    q0 = __builtin_amdgcn_mfma_f32_16x16x32_bf16(A0h, Bl, q0, 0, 0, 0);
    f32x4 p1 = __builtin_amdgcn_mfma_f32_16x16x32_bf16(A1h, Bh, z4, 0, 0, 0);
    f32x4 q1 = __builtin_amdgcn_mfma_f32_16x16x32_bf16(A1l, Bh, z4, 0, 0, 0);
    q1 = __builtin_amdgcn_mfma_f32_16x16x32_bf16(A1h, Bl, q1, 0, 0, 0);
    c0 = p0 + q0;
    c1 = p1 + q1;
  };

  // ---- pipeline: trig one patch ahead, meas one patch behind ----
  float2 t0 = *(const float2*)(xb);
  float2 t1 = *(const float2*)(xb + 28);
  trig(t0, t1);                         // params for patch 0
  t0 = *(const float2*)(xb + 2);        // patch 1 values
  t1 = *(const float2*)(xb + 30);
  step();                               // patch 0
  trig(t0, t1);                         // params for patch 1
  t0 = *(const float2*)(xb + 4);        // patch 2 values
  t1 = *(const float2*)(xb + 32);
  int nrr = 0, ncc = 3;                 // next load = patch 3
  __bf16* fp = fb;

#pragma unroll 2
  for (int it = 1; it < 196; ++it) {
    const float* np = (it < 194) ? (xb + 56 * nrr + 2 * ncc) : xb;
    const float2 n0 = *(const float2*)np;
    const float2 n1 = *(const float2*)(np + 28);
    ncc++;
    if (ncc == 14) { ncc = 0; nrr++; }

    meas(fp); fp += 4;                  // state after patch it-1
    step();                             // patch it (uses current params)
    trig(t0, t1);                       // params for patch it+1
    t0 = n0; t1 = n1;
  }
  meas(fp);

  // zero the K padding 784..800
  if (kg == 0) {
    *(uint4*)(fb + 784) = (uint4){0, 0, 0, 0};
    *(uint4*)(fb + 792) = (uint4){0, 0, 0, 0};
  }
}

// ========== bf16 MFMA NT GEMM: C(bf16) = A*B^T + bias, fused BN stats ======
// 1D grid + bijective XCD swizzle (nwg = 512, divisible by 8).
// Stats (sum, sumsq per column) computed from fp32 accumulators.
#define GBM 128
#define GBN 64
#define GBK 32

__device__ __forceinline__ void gld16(const void* g, void* l) {
  __builtin_amdgcn_global_load_lds(
      (const __attribute__((address_space(1))) unsigned int*)g,
      (__attribute__((address_space(3))) unsigned int*)l, 16, 0, 0);
}

__global__ __launch_bounds__(256) void gemm_bf16_nt(
    const __bf16* __restrict__ A, const __bf16* __restrict__ B,
    const float* __restrict__ bias, __bf16* __restrict__ C,
    int M, int N, int K, float* __restrict__ gstats) {
  __shared__ char lds[24576];
  const int tid = threadIdx.x;
  const int nwg = gridDim.x;
  const int sid = (blockIdx.x & 7) * (nwg >> 3) + (blockIdx.x >> 3);
  const int bm = (sid >> 2) * GBM;      // N/GBN == 4
  const int bn = (sid & 3) * GBN;
  const int NK = K / GBK;
  const size_t lda = (size_t)K * 2;

  const int srow = tid >> 2;
  const int lc16 = tid & 3;
  const int ag0 = lc16 ^ ((srow >> 1) & 3);
  const int ag1 = lc16 ^ (((srow + 64) >> 1) & 3);
  const char* a0p = (const char*)A + (size_t)(bm + srow) * lda + ag0 * 16;
  const char* a1p = (const char*)A + (size_t)(bm + 64 + srow) * lda + ag1 * 16;
  const char* b0p = (const char*)B + (size_t)(bn + srow) * lda + ag0 * 16;

  const int wid = tid >> 6, lane = tid & 63;
  const int wr = wid >> 1, wc = wid & 1;
  const int ln15 = lane & 15, ln4 = lane >> 4;
  int aoff[4], boff[2];
#pragma unroll
  for (int m = 0; m < 4; m++) {
    const int row = wr * 64 + m * 16 + ln15;
    aoff[m] = row * 64 + ((ln4 ^ ((row >> 1) & 3)) * 16);
  }
#pragma unroll
  for (int n = 0; n < 2; n++) {
    const int row = wc * 32 + n * 16 + ln15;
    boff[n] = 16384 + row * 64 + ((ln4 ^ ((row >> 1) & 3)) * 16);
  }

  f32x4 acc[4][2];
#pragma unroll
  for (int m = 0; m < 4; m++)
#pragma unroll
    for (int n = 0; n < 2; n++) acc[m][n] = (f32x4){0.f, 0.f, 0.f, 0.f};

  auto stage = [&](int buf, int kt) {
    const size_t kb = (size_t)kt * GBK * 2;
    char* as = lds + buf * 8192 + tid * 16;
    char* bs = lds + 16384 + buf * 4096 + tid * 16;
    gld16(a0p + kb, as);
    gld16(a1p + kb, as + 4096);
    gld16(b0p + kb, bs);
  };

  stage(0, 0);
  for (int kt = 0; kt < NK; kt++) {
    __syncthreads();
    if (kt + 1 < NK) stage((kt + 1) & 1, kt + 1);
    const int ab = (kt & 1) * 8192, bb = (kt & 1) * 4096;
    bf16x8 af[4], bfr[2];
#pragma unroll
    for (int m = 0; m < 4; m++) af[m] = *(const bf16x8*)(lds + ab + aoff[m]);
#pragma unroll
    for (int n = 0; n < 2; n++) bfr[n] = *(const bf16x8*)(lds + bb + boff[n]);
#pragma unroll
    for (int m = 0; m < 4; m++)
#pragma unroll
      for (int n = 0; n < 2; n++)
        acc[m][n] = __builtin_amdgcn_mfma_f32_16x16x32_bf16(af[m], bfr[n], acc[m][n], 0, 0, 0);
  }

  // epilogue: bf16 C write + per-block column stats (sum, sumsq from fp32)
  float csum[2], csq[2];
#pragma unroll
  for (int n = 0; n < 2; n++) {
    const int ccol = bn + wc * 32 + n * 16 + ln15;
    const float bv = bias[ccol];
    float s = 0.f, ss = 0.f;
#pragma unroll
    for (int m = 0; m < 4; m++) {
      const int crow = bm + wr * 64 + m * 16 + ln4 * 4;
#pragma unroll
      for (int r = 0; r < 4; r++) {
        const float v = acc[m][n][r] + bv;
        C[(size_t)(crow + r) * N + ccol] = (__bf16)v;
        s += v; ss += v * v;
      }
    }
    csum[n] = s; csq[n] = ss;
  }
  __syncthreads();                       // LDS staging reads done -> reuse
  float* sred = (float*)lds;             // [2 stats][4 wid][4 ln4][32 col]
#pragma unroll
  for (int n = 0; n < 2; n++) {
    const int slot = wid * 128 + ln4 * 32 + n * 16 + ln15;
    sred[slot] = csum[n];
    sred[512 + slot] = csq[n];
  }
  __syncthreads();
  if (tid < 128) {
    const int colb = tid & 63, which = tid >> 6;
    const int wcc = colb >> 5, c31 = colb & 31;
    float a = 0.f;
    const int base = which * 512 + c31;
#pragma unroll
    for (int w2_ = 0; w2_ < 2; w2_++)
#pragma unroll
      for (int l4 = 0; l4 < 4; l4++)
        a += sred[base + (w2_ * 2 + wcc) * 128 + l4 * 32];
    atomicAdd(&gstats[(bn + colb) * 2 + which], a);
  }
}

// ====== BN1+ReLU: reads pre-BN bf16 h1p, finalizes stats in-block ==========
__global__ __launch_bounds__(256) void bn1_relu(
    const __bf16* __restrict__ h1p, __bf16* __restrict__ h1b,
    const float* __restrict__ gstats, const float* __restrict__ g,
    const float* __restrict__ be) {
  __shared__ float as[NH], cs[NH];
  {
    const int t = threadIdx.x;
    const float s = gstats[t * 2], ss = gstats[t * 2 + 1];
    const float mean = s * (1.f / 16384.f);
    const float var = ss * (1.f / 16384.f) - mean * mean;
    const float a = g[t] * rsqrtf(var + 1e-5f);
    as[t] = a;
    cs[t] = be[t] - mean * a;
  }
  __syncthreads();
  const size_t i = (size_t)blockIdx.x * 256 + threadIdx.x;  // bf16x8 index
  const bf16x8 v = *(const bf16x8*)(h1p + i * 8);
  const int colb = (int)((i * 8) & (NH - 1));
  bf16x8 o;
#pragma unroll
  for (int j = 0; j < 8; j++)
    o[j] = (__bf16)fmaxf(fmaf((float)v[j], as[colb + j], cs[colb + j]), 0.f);
  *(bf16x8*)(h1b + i * 8) = o;
}

// ====== fused tail: BN2(in-block finalize) + ReLU + residual + head ========
__global__ __launch_bounds__(256) void tail_fused(
    const __bf16* __restrict__ h2b, const __bf16* __restrict__ h1b,
    const float* __restrict__ gstats, const float* __restrict__ g,
    const float* __restrict__ be, const float* __restrict__ w3,
    const float* __restrict__ b3, float* __restrict__ out) {
  __shared__ float w3s[NCLS * NH];
  __shared__ float as[NH], cs[NH];
  for (int i = threadIdx.x; i < NCLS * NH; i += 256) w3s[i] = w3[i];
  {
    const int t = threadIdx.x;
    const float s = gstats[t * 2], ss = gstats[t * 2 + 1];
    const float mean = s * (1.f / 16384.f);
    const float var = ss * (1.f / 16384.f) - mean * mean;
    const float a = g[t] * rsqrtf(var + 1e-5f);
    as[t] = a;
    cs[t] = be[t] - mean * a;
  }
  __syncthreads();

  const int m = blockIdx.x * 256 + threadIdx.x;
  const __bf16* hr = h2b + (size_t)m * NH;
  const __bf16* rr = h1b + (size_t)m * NH;
  float acc[NCLS];
#pragma unroll
  for (int n = 0; n < NCLS; n++) acc[n] = b3[n];

  for (int k = 0; k < NH; k += 8) {
    const bf16x8 hv = *(const bf16x8*)(hr + k);
    const bf16x8 rv = *(const bf16x8*)(rr + k);
    float v[8];
#pragma unroll
    for (int j = 0; j < 8; j++)
      v[j] = fmaxf(fmaf((float)hv[j], as[k + j], cs[k + j]), 0.f) + (float)rv[j];
#pragma unroll
    for (int n = 0; n < NCLS; n++) {
      float d = 0.f;
#pragma unroll
      for (int j = 0; j < 8; j++) d = fmaf(v[j], w3s[n * NH + k + j], d);
      acc[n] += d;
    }
  }

  float mx = acc[0];
#pragma unroll
  for (int n = 1; n < NCLS; n++) mx = fmaxf(mx, acc[n]);
  float se = 0.f;
#pragma unroll
  for (int n = 0; n < NCLS; n++) se += expf(acc[n] - mx);
  const float lse = logf(se) + mx;
#pragma unroll
  for (int n = 0; n < NCLS; n++) out[(size_t)m * NCLS + n] = acc[n] - lse;
}

// =========================== launch ========================================
extern "C" void kernel_launch(void* const* d_in, const int* in_sizes, int n_in,
                              void* d_out, int out_size, void* d_ws, size_t ws_size,
                              hipStream_t stream) {
  const float* x   = (const float*)d_in[0];
  const float* qp  = (const float*)d_in[1];
  const float* w1  = (const float*)d_in[2];
  const float* b1  = (const float*)d_in[3];
  const float* g1  = (const float*)d_in[4];
  const float* be1 = (const float*)d_in[5];
  const float* w2  = (const float*)d_in[6];
  const float* b2  = (const float*)d_in[7];
  const float* g2  = (const float*)d_in[8];
  const float* be2 = (const float*)d_in[9];
  const float* w3  = (const float*)d_in[10];
  const float* b3  = (const float*)d_in[11];
  float* out = (float*)d_out;

  char* w = (char*)d_ws;
  __bf16* feats = (__bf16*)w;                         // 26,214,400
  __bf16* h1p   = (__bf16*)(w + 26214400);            //  8,388,608 (pre-BN1)
  __bf16* h1b   = (__bf16*)(w + 34603008);            //  8,388,608 (post-BN1)
  __bf16* h2b   = (__bf16*)(w + 42991616);            //  8,388,608 (pre-BN2)
  __bf16* w1b   = (__bf16*)(w + 51380224);            //    409,600
  __bf16* w2b   = (__bf16*)(w + 51789824);            //    131,072
  float*  gs1   = (float*)(w + 51920896);             //      2,048
  float*  gs2   = (float*)(w + 51922944);             //      2,048
  __bf16* Abuf  = (__bf16*)(w + 51924992);            //      4,096

  prep_kernel<<<289, 256, 0, stream>>>(qp, w1, w2, Abuf, w1b, w2b, gs1, gs2);
  quanv_mfma<<<BQ / 64, 256, 0, stream>>>(x, Abuf, feats);

  gemm_bf16_nt<<<(BQ / GBM) * (NH / GBN), 256, 0, stream>>>(
      feats, w1b, b1, h1p, BQ, NH, KFP, gs1);
  bn1_relu<<<(BQ * NH / 8) / 256, 256, 0, stream>>>(h1p, h1b, gs1, g1, be1);

  gemm_bf16_nt<<<(BQ / GBM) * (NH / GBN), 256, 0, stream>>>(
      h1b, w2b, b2, h2b, BQ, NH, NH, gs2);

  tail_fused<<<BQ / 256, 256, 0, stream>>>(h2b, h1b, gs2, g2, be2, w3, b3, out);
}

// Round 12
// 194.401 us; speedup vs baseline: 1.5112x; 1.0592x over previous
//
#include <hip/hip_runtime.h>
#include <math.h>

#define BQ 16384      // batch
#define KFP 800       // padded w1 K dim (196*4 = 784, +16 zero pad)
#define NH 256        // hidden dim
#define NCLS 10

typedef float f32x4 __attribute__((ext_vector_type(4)));
typedef unsigned int u32x2 __attribute__((ext_vector_type(2)));
typedef unsigned int u32x4 __attribute__((ext_vector_type(4)));
typedef __bf16 bf16x8 __attribute__((ext_vector_type(8)));
typedef __bf16 bf16x4 __attribute__((ext_vector_type(4)));

// ===================== prep: build U + weight cvt + zero stats =============
// Amp index bits: wire w <-> bit (8>>w), matching reference flatten order.
// Lane mapping for quanv: bit5 = w0 amp-bit, bit4 = ReIm.
// Abuf layout: flat f: m=f&7, row=(f>>3)&15, kg=(f>>7)&3, hl=(f>>9)&1, t=f>>10.

template<int ST>
__device__ __forceinline__ void u_ry(float* sr, float* si, float c, float s) {
#pragma unroll
  for (int i = 0; i < 16; i++) {
    if (i & ST) continue;
    const int j = i | ST;
    const float a0r = sr[i], a0i = si[i], a1r = sr[j], a1i = si[j];
    sr[i] = c * a0r - s * a1r;  si[i] = c * a0i - s * a1i;
    sr[j] = s * a0r + c * a1r;  si[j] = s * a0i + c * a1i;
  }
}
template<int ST>
__device__ __forceinline__ void u_rz(float* sr, float* si, float c, float s) {
#pragma unroll
  for (int i = 0; i < 16; i++) {
    const float pz = (i & ST) ? s : -s;
    const float ar = sr[i], ai = si[i];
    sr[i] = c * ar - pz * ai;
    si[i] = c * ai + pz * ar;
  }
}
template<int SC, int STG>
__device__ __forceinline__ void u_cnot(float* sr, float* si) {
#pragma unroll
  for (int i = 0; i < 16; i++) {
    if (!(i & SC) || (i & STG)) continue;
    const int j = i | STG;
    float t;
    t = sr[i]; sr[i] = sr[j]; sr[j] = t;
    t = si[i]; si[i] = si[j]; si[j] = t;
  }
}

__global__ __launch_bounds__(256) void prep_kernel(
    const float* __restrict__ qp, const float* __restrict__ w1,
    const float* __restrict__ w2, __bf16* __restrict__ Abuf,
    __bf16* __restrict__ w1b, __bf16* __restrict__ w2b,
    float* __restrict__ gs1, float* __restrict__ gs2) {
  const int bid = blockIdx.x;
  const int tid = threadIdx.x;
  if (bid == 0) {
    gs1[tid] = 0.f; gs1[256 + tid] = 0.f;
    gs2[tid] = 0.f; gs2[256 + tid] = 0.f;
    __shared__ float Ur[16][16], Ui[16][16];
    if (tid < 16) {
      float sr[16], si[16];
#pragma unroll
      for (int i = 0; i < 16; i++) { sr[i] = (i == tid) ? 1.f : 0.f; si[i] = 0.f; }
#pragma unroll
      for (int l = 0; l < 2; l++) {
        { const float t = qp[l*8 + 0] * 0.5f; u_ry<8>(sr, si, cosf(t), sinf(t)); }
        { const float t = qp[l*8 + 1] * 0.5f; u_rz<8>(sr, si, cosf(t), sinf(t)); }
        { const float t = qp[l*8 + 2] * 0.5f; u_ry<4>(sr, si, cosf(t), sinf(t)); }
        { const float t = qp[l*8 + 3] * 0.5f; u_rz<4>(sr, si, cosf(t), sinf(t)); }
        { const float t = qp[l*8 + 4] * 0.5f; u_ry<2>(sr, si, cosf(t), sinf(t)); }
        { const float t = qp[l*8 + 5] * 0.5f; u_rz<2>(sr, si, cosf(t), sinf(t)); }
        { const float t = qp[l*8 + 6] * 0.5f; u_ry<1>(sr, si, cosf(t), sinf(t)); }
        { const float t = qp[l*8 + 7] * 0.5f; u_rz<1>(sr, si, cosf(t), sinf(t)); }
        u_cnot<8, 4>(sr, si);
        u_cnot<4, 2>(sr, si);
        u_cnot<2, 1>(sr, si);
      }
#pragma unroll
      for (int r = 0; r < 16; r++) { Ur[r][tid] = sr[r]; Ui[r][tid] = si[r]; }
    }
    __syncthreads();
    for (int f = tid; f < 2048; f += 256) {
      const int m   = f & 7;
      const int row = (f >> 3) & 15;
      const int kg  = (f >> 7) & 3;
      const int hl  = (f >> 9) & 1;
      const int t   = (f >> 10) & 1;
      const int k   = kg * 8 + m;
      const int ri_o  = (row >> 2) & 1;
      const int amp_o = ((row >> 3) & 1) * 8 + t * 4 + (row & 3);
      const int ri_i  = (k >> 3) & 1;
      const int amp_i = ((k >> 4) & 1) * 8 + (m >> 2) * 4 + (m & 3);
      const float u_r = Ur[amp_o][amp_i], u_i = Ui[amp_o][amp_i];
      float v = (ri_o == 0) ? ((ri_i == 0) ? u_r : -u_i)
                            : ((ri_i == 0) ? u_i : u_r);
      if (hl) {
        const __bf16 hb = (__bf16)v;
        v = v - (float)hb;
      }
      Abuf[f] = (__bf16)v;
    }
  } else if (bid <= 256) {
    const int r = bid - 1;
    for (int c = tid; c < KFP; c += 256)
      w1b[r * KFP + c] = (c < 784) ? (__bf16)w1[r * 784 + c] : (__bf16)0.f;
  } else {
    const int base = (bid - 257) * 2048 + tid * 8;
    const float4 v0 = *(const float4*)(w2 + base);
    const float4 v1 = *(const float4*)(w2 + base + 4);
    bf16x8 o = {(__bf16)v0.x, (__bf16)v0.y, (__bf16)v0.z, (__bf16)v0.w,
                (__bf16)v1.x, (__bf16)v1.y, (__bf16)v1.z, (__bf16)v1.w};
    *(bf16x8*)(w2b + base) = o;
  }
}

// ============ quanv via MFMA, FUSED with GEMM1 + BN1-stats =================
// Round-9 quanv core (compiler-cvt split). Features never touch global:
// each lane packs its element's (z0..z3) into an A-fragment slot (selected
// by patch&7 vs kg); every 8 patches -> 16 MFMAs vs preloaded w1 B-frags.
// Epilogue: BN1 stats (LDS reduce + atomics), bias + bf16 transpose, h1p.

__device__ __forceinline__ float swz16(float v) {
  return __int_as_float(__builtin_amdgcn_ds_swizzle(__float_as_int(v), 0x401F));
}
__device__ __forceinline__ float plsum(float v) {
  const u32x2 r = __builtin_amdgcn_permlane32_swap(
      __float_as_uint(v), __float_as_uint(v), false, false);
  return __uint_as_float(r.x) + __uint_as_float(r.y);
}
__device__ __forceinline__ float plpick(float v, bool r0sel) {
  const u32x2 r = __builtin_amdgcn_permlane32_swap(
      __float_as_uint(v), __float_as_uint(v), false, false);
  return __uint_as_float(r0sel ? r.x : r.y);
}
__device__ __forceinline__ unsigned bfbits(float v) {
  return (unsigned)__builtin_bit_cast(unsigned short, (__bf16)v);
}

__global__ __launch_bounds__(256, 1) void quanv_fused(
    const float* __restrict__ x, const __bf16* __restrict__ Abuf,
    const __bf16* __restrict__ w1b, const float* __restrict__ b1,
    __bf16* __restrict__ h1p, float* __restrict__ gs1) {
  __shared__ char qlds[33792];
  const int tid = threadIdx.x;
  const int l = tid & 63;
  const int wv = tid >> 6;
  const int col = l & 15;        // element within wave / MFMA row|col index
  const int kg = l >> 4;         // k-group
  const int b = blockIdx.x * 64 + wv * 16 + col;
  const float* xb = x + (size_t)b * 784;
  const float sg0 = (l & 32) ? 1.f : -1.f;   // wire0 amp-bit sign (b5)

  const u32x2 pt = __builtin_amdgcn_permlane32_swap((unsigned)l, (unsigned)l,
                                                    false, false);
  const bool p32r0 = (pt.x == (unsigned)(l ^ 32));

  // U fragments (held in VGPRs for the whole kernel)
  const bf16x8* Ab = (const bf16x8*)Abuf;
  const bf16x8 A0h = Ab[(0 * 4 + kg) * 16 + col];
  const bf16x8 A0l = Ab[(1 * 4 + kg) * 16 + col];
  const bf16x8 A1h = Ab[(2 * 4 + kg) * 16 + col];
  const bf16x8 A1l = Ab[(3 * 4 + kg) * 16 + col];

  f32x4 c0 = {(kg == 0) ? 1.f : 0.f, 0.f, 0.f, 0.f};
  f32x4 c1 = {0.f, 0.f, 0.f, 0.f};
  const f32x4 z4 = {0.f, 0.f, 0.f, 0.f};

  // GEMM1 state: A-frag under construction, w1 B-frags, 16x16-col acc
  u32x4 frag = {0, 0, 0, 0};
  bf16x8 bfrag[16];
  f32x4 acc[16];
#pragma unroll
  for (int nt = 0; nt < 16; nt++) acc[nt] = z4;

  auto loadB = [&](int w8) {
#pragma unroll
    for (int nt = 0; nt < 16; nt++)
      bfrag[nt] = *(const bf16x8*)(w1b + (size_t)(nt * 16 + col) * KFP +
                                   w8 * 32 + kg * 8);
  };
  auto burst = [&]() {
    const bf16x8 fa = __builtin_bit_cast(bf16x8, frag);
#pragma unroll
    for (int nt = 0; nt < 16; nt++)
      acc[nt] = __builtin_amdgcn_mfma_f32_16x16x32_bf16(fa, bfrag[nt], acc[nt], 0, 0, 0);
    frag = (u32x4){0, 0, 0, 0};
  };

  // pipelined per-patch params: tangents (sign-folded for wire0) + cos product
  float ts0, tw1, tw2, tw3, gsc;
  auto trig = [&](float2 a, float2 b2) {
    const float h0 = a.x * 0.5f, h1 = a.y * 0.5f;
    const float h2 = b2.x * 0.5f, h3 = b2.y * 0.5f;
    const float c0_ = __cosf(h0), s0_ = __sinf(h0);
    const float c1_ = __cosf(h1), s1_ = __sinf(h1);
    const float c2_ = __cosf(h2), s2_ = __sinf(h2);
    const float c3_ = __cosf(h3), s3_ = __sinf(h3);
    ts0 = sg0 * __fdividef(s0_, c0_);     // angles in [0,0.5] rad -> cos>=0.878
    tw1 = __fdividef(s1_, c1_);
    tw2 = __fdividef(s2_, c2_);
    tw3 = __fdividef(s3_, c3_);
    gsc = (c0_ * c1_) * (c2_ * c3_);
  };

  // measure state (after patch mit) and pack into A-frag slot
  auto meas = [&](int mit) {
    const float sq0 = c0.x * c0.x, sq1 = c0.y * c0.y;
    const float sq2 = c0.z * c0.z, sq3 = c0.w * c0.w;
    const float sq4 = c1.x * c1.x, sq5 = c1.y * c1.y;
    const float sq6 = c1.z * c1.z, sq7 = c1.w * c1.w;
    const float s01 = sq0 + sq1, s23 = sq2 + sq3;
    const float s45 = sq4 + sq5, s67 = sq6 + sq7;
    const float d01 = sq0 - sq1, d23 = sq2 - sq3;
    const float d45 = sq4 - sq5, d67 = sq6 - sq7;
    const float z3 = (d01 + d23) + (d45 + d67);   // sign by w3
    const float z2 = (s01 - s23) + (s45 - s67);   // sign by w2
    const float q03 = s01 + s23, q47 = s45 + s67;
    const float z1 = q03 - q47;                   // sign by w1 (chain)
    const float T  = q03 + q47;
    const float z3a = z3 + swz16(z3);             // ReIm combine (bit4)
    const float z2a = z2 + swz16(z2);
    const float z1a = z1 + swz16(z1);
    // weight by -sg0 BEFORE pair sum: z0 = Ta(bit clear) - Ta(bit set)
    const float Ta  = -sg0 * (T + swz16(T));
    const float z3f = plsum(z3a);                 // w0 combine (bit5); values
    const float z2f = plsum(z2a);                 // uniform across the quad
    const float z1f = plsum(z1a);
    const float z0f = plsum(Ta);
    // pack (z0..z3) bf16 into frag slot: k' = (mit&7)*4 + wire
    const unsigned zlo = (bfbits(z1f) << 16) | bfbits(z0f);
    const unsigned zhi = (bfbits(z3f) << 16) | bfbits(z2f);
    const int p = mit & 7;
    const bool selA = ((p >> 1) == kg) & ((p & 1) == 0);
    const bool selB = ((p >> 1) == kg) & ((p & 1) == 1);
    frag.x = selA ? zlo : frag.x;
    frag.y = selA ? zhi : frag.y;
    frag.z = selB ? zlo : frag.z;
    frag.w = selB ? zhi : frag.w;
  };

  // E(vals) in tan form + deferred scale + 6 MFMAs (depth-2 chains)
  auto step = [&]() {
    float S[8] = {c0.x, c0.y, c0.z, c0.w, c1.x, c1.y, c1.z, c1.w};
#pragma unroll
    for (int j = 0; j < 4; j++) {          // wire1: pairs (j, j+4)
      const float a = S[j];
      S[j]     = fmaf(-tw1, S[4 + j], S[j]);
      S[4 + j] = fmaf( tw1, a,        S[4 + j]);
    }
#pragma unroll
    for (int base = 0; base < 8; base += 4)   // wire2: pairs (i, i^2)
#pragma unroll
      for (int j = 0; j < 2; j++) {
        const int i0 = base + j, i1 = base + j + 2;
        const float a = S[i0];
        S[i0] = fmaf(-tw2, S[i1], S[i0]);
        S[i1] = fmaf( tw2, a,     S[i1]);
      }
#pragma unroll
    for (int i0 = 0; i0 < 8; i0 += 2) {      // wire3: pairs (i, i^1)
      const float a = S[i0];
      S[i0]     = fmaf(-tw3, S[i0 + 1], S[i0]);
      S[i0 + 1] = fmaf( tw3, a,         S[i0 + 1]);
    }
#pragma unroll
    for (int i = 0; i < 8; i++) {            // wire0: cross-lane bit5
      const float P = plpick(S[i], p32r0);
      S[i] = fmaf(ts0, P, S[i]);
    }
    // deferred scale + hi/lo split (compiler packs cvt)
    bf16x8 Bh, Bl;
#pragma unroll
    for (int i = 0; i < 8; i++) {
      const float GS = gsc * S[i];
      const __bf16 hb = (__bf16)GS;
      Bh[i] = hb;
      Bl[i] = (__bf16)(GS - (float)hb);
    }
    f32x4 p0 = __builtin_amdgcn_mfma_f32_16x16x32_bf16(A0h, Bh, z4, 0, 0, 0);
    f32x4 q0 = __builtin_amdgcn_mfma_f32_16x16x32_bf16(A0l, Bh, z4, 0, 0, 0);
    q0 = __builtin_amdgcn_mfma_f32_16x16x32_bf16(A0h, Bl, q0, 0, 0, 0);
    f32x4 p1 = __builtin_amdgcn_mfma_f32_16x16x32_bf16(A1h, Bh, z4, 0, 0, 0);
    f32x4 q1 = __builtin_amdgcn_mfma_f32_16x16x32_bf16(A1l, Bh, z4, 0, 0, 0);
    q1 = __builtin_amdgcn_mfma_f32_16x16x32_bf16(A1h, Bl, q1, 0, 0, 0);
    c0 = p0 + q0;
    c1 = p1 + q1;
  };

  // ---- pipeline: trig one patch ahead, meas one patch behind ----
  loadB(0);                             // w1 B-frags for window 0
  float2 t0 = *(const float2*)(xb);
  float2 t1 = *(const float2*)(xb + 28);
  trig(t0, t1);                         // params for patch 0
  t0 = *(const float2*)(xb + 2);        // patch 1 values
  t1 = *(const float2*)(xb + 30);
  step();                               // patch 0
  trig(t0, t1);                         // params for patch 1
  t0 = *(const float2*)(xb + 4);        // patch 2 values
  t1 = *(const float2*)(xb + 32);
  int nrr = 0, ncc = 3;                 // next load = patch 3

  for (int it = 1; it < 196; ++it) {
    const float* np = (it < 194) ? (xb + 56 * nrr + 2 * ncc) : xb;
    const float2 n0 = *(const float2*)np;
    const float2 n1 = *(const float2*)(np + 28);
    ncc++;
    if (ncc == 14) { ncc = 0; nrr++; }

    meas(it - 1);                       // pack state after patch it-1
    if ((it & 7) == 0) {                // window (it>>3)-1 complete
      burst();
      loadB(it >> 3);                   // prefetch next window's w1 frags
    }
    step();                             // patch it (uses current params)
    trig(t0, t1);                       // params for patch it+1
    t0 = n0; t1 = n1;
  }
  meas(195);
  burst();                              // partial window 24 (kg>=2 frags = 0)

  // ---- BN1 stats: per-block column sum/sumsq -> atomics ----
  float bv[16];
#pragma unroll
  for (int nt = 0; nt < 16; nt++) bv[nt] = b1[nt * 16 + col];
  float* sredS = (float*)qlds;          // [16][256]
  float* sredQ = sredS + 4096;          // [16][256]
#pragma unroll
  for (int nt = 0; nt < 16; nt++) {
    float s = 0.f, q = 0.f;
#pragma unroll
    for (int r = 0; r < 4; r++) {
      const float v = acc[nt][r] + bv[nt];
      s += v; q += v * v;
    }
    sredS[(wv * 4 + kg) * 256 + nt * 16 + col] = s;
    sredQ[(wv * 4 + kg) * 256 + nt * 16 + col] = q;
  }
  __syncthreads();
  {
    float s = 0.f, q = 0.f;
#pragma unroll
    for (int r = 0; r < 16; r++) {
      s += sredS[r * 256 + tid];
      q += sredQ[r * 256 + tid];
    }
    atomicAdd(&gs1[tid * 2], s);
    atomicAdd(&gs1[tid * 2 + 1], q);
  }
  __syncthreads();

  // ---- bias + bf16 transpose through LDS, coalesced h1p store ----
  // D layout: lane holds col = nt*16+col(l&15), rows = (l>>4)*4 + r
  __bf16* tile = (__bf16*)qlds;         // [64][264] (+8 pad breaks banks)
#pragma unroll
  for (int nt = 0; nt < 16; nt++)
#pragma unroll
    for (int r = 0; r < 4; r++)
      tile[(wv * 16 + kg * 4 + r) * 264 + nt * 16 + col] =
          (__bf16)(acc[nt][r] + bv[nt]);
  __syncthreads();
  for (int pass = 0; pass < 8; pass++) {
    const int idx = pass * 256 + tid;   // 2048 chunks of 8 bf16
    const int row = idx >> 5, c8 = idx & 31;
    const bf16x8 vv = *(const bf16x8*)&tile[row * 264 + c8 * 8];
    *(bf16x8*)(h1p + ((size_t)(blockIdx.x * 64 + row)) * 256 + c8 * 8) = vv;
  }
}

// ========== bf16 MFMA NT GEMM (GEMM2): C(bf16) = A*B^T + bias, BN stats ====
#define GBM 128
#define GBN 64
#define GBK 32

__device__ __forceinline__ void gld16(const void* g, void* l) {
  __builtin_amdgcn_global_load_lds(
      (const __attribute__((address_space(1))) unsigned int*)g,
      (__attribute__((address_space(3))) unsigned int*)l, 16, 0, 0);
}

__global__ __launch_bounds__(256) void gemm_bf16_nt(
    const __bf16* __restrict__ A, const __bf16* __restrict__ B,
    const float* __restrict__ bias, __bf16* __restrict__ C,
    int M, int N, int K, float* __restrict__ gstats) {
  __shared__ char lds[24576];
  const int tid = threadIdx.x;
  const int nwg = gridDim.x;
  const int sid = (blockIdx.x & 7) * (nwg >> 3) + (blockIdx.x >> 3);
  const int bm = (sid >> 2) * GBM;      // N/GBN == 4
  const int bn = (sid & 3) * GBN;
  const int NK = K / GBK;
  const size_t lda = (size_t)K * 2;

  const int srow = tid >> 2;
  const int lc16 = tid & 3;
  const int ag0 = lc16 ^ ((srow >> 1) & 3);
  const int ag1 = lc16 ^ (((srow + 64) >> 1) & 3);
  const char* a0p = (const char*)A + (size_t)(bm + srow) * lda + ag0 * 16;
  const char* a1p = (const char*)A + (size_t)(bm + 64 + srow) * lda + ag1 * 16;
  const char* b0p = (const char*)B + (size_t)(bn + srow) * lda + ag0 * 16;

  const int wid = tid >> 6, lane = tid & 63;
  const int wr = wid >> 1, wc = wid & 1;
  const int ln15 = lane & 15, ln4 = lane >> 4;
  int aoff[4], boff[2];
#pragma unroll
  for (int m = 0; m < 4; m++) {
    const int row = wr * 64 + m * 16 + ln15;
    aoff[m] = row * 64 + ((ln4 ^ ((row >> 1) & 3)) * 16);
  }
#pragma unroll
  for (int n = 0; n < 2; n++) {
    const int row = wc * 32 + n * 16 + ln15;
    boff[n] = 16384 + row * 64 + ((ln4 ^ ((row >> 1) & 3)) * 16);
  }

  f32x4 acc[4][2];
#pragma unroll
  for (int m = 0; m < 4; m++)
#pragma unroll
    for (int n = 0; n < 2; n++) acc[m][n] = (f32x4){0.f, 0.f, 0.f, 0.f};

  auto stage = [&](int buf, int kt) {
    const size_t kb = (size_t)kt * GBK * 2;
    char* as = lds + buf * 8192 + tid * 16;
    char* bs = lds + 16384 + buf * 4096 + tid * 16;
    gld16(a0p + kb, as);
    gld16(a1p + kb, as + 4096);
    gld16(b0p + kb, bs);
  };

  stage(0, 0);
  for (int kt = 0; kt < NK; kt++) {
    __syncthreads();
    if (kt + 1 < NK) stage((kt + 1) & 1, kt + 1);
    const int ab = (kt & 1) * 8192, bb = (kt & 1) * 4096;
    bf16x8 af[4], bfr[2];
#pragma unroll
    for (int m = 0; m < 4; m++) af[m] = *(const bf16x8*)(lds + ab + aoff[m]);
#pragma unroll
    for (int n = 0; n < 2; n++) bfr[n] = *(const bf16x8*)(lds + bb + boff[n]);
#pragma unroll
    for (int m = 0; m < 4; m++)
#pragma unroll
      for (int n = 0; n < 2; n++)
        acc[m][n] = __builtin_amdgcn_mfma_f32_16x16x32_bf16(af[m], bfr[n], acc[m][n], 0, 0, 0);
  }

  float csum[2], csq[2];
#pragma unroll
  for (int n = 0; n < 2; n++) {
    const int ccol = bn + wc * 32 + n * 16 + ln15;
    const float bv = bias[ccol];
    float s = 0.f, ss = 0.f;
#pragma unroll
    for (int m = 0; m < 4; m++) {
      const int crow = bm + wr * 64 + m * 16 + ln4 * 4;
#pragma unroll
      for (int r = 0; r < 4; r++) {
        const float v = acc[m][n][r] + bv;
        C[(size_t)(crow + r) * N + ccol] = (__bf16)v;
        s += v; ss += v * v;
      }
    }
    csum[n] = s; csq[n] = ss;
  }
  __syncthreads();
  float* sred = (float*)lds;
#pragma unroll
  for (int n = 0; n < 2; n++) {
    const int slot = wid * 128 + ln4 * 32 + n * 16 + ln15;
    sred[slot] = csum[n];
    sred[512 + slot] = csq[n];
  }
  __syncthreads();
  if (tid < 128) {
    const int colb = tid & 63, which = tid >> 6;
    const int wcc = colb >> 5, c31 = colb & 31;
    float a = 0.f;
    const int base = which * 512 + c31;
#pragma unroll
    for (int w2_ = 0; w2_ < 2; w2_++)
#pragma unroll
      for (int l4 = 0; l4 < 4; l4++)
        a += sred[base + (w2_ * 2 + wcc) * 128 + l4 * 32];
    atomicAdd(&gstats[(bn + colb) * 2 + which], a);
  }
}

// ====== BN1+ReLU: reads pre-BN bf16 h1p, finalizes stats in-block ==========
__global__ __launch_bounds__(256) void bn1_relu(
    const __bf16* __restrict__ h1p, __bf16* __restrict__ h1b,
    const float* __restrict__ gstats, const float* __restrict__ g,
    const float* __restrict__ be) {
  __shared__ float as[NH], cs[NH];
  {
    const int t = threadIdx.x;
    const float s = gstats[t * 2], ss = gstats[t * 2 + 1];
    const float mean = s * (1.f / 16384.f);
    const float var = ss * (1.f / 16384.f) - mean * mean;
    const float a = g[t] * rsqrtf(var + 1e-5f);
    as[t] = a;
    cs[t] = be[t] - mean * a;
  }
  __syncthreads();
  const size_t i = (size_t)blockIdx.x * 256 + threadIdx.x;  // bf16x8 index
  const bf16x8 v = *(const bf16x8*)(h1p + i * 8);
  const int colb = (int)((i * 8) & (NH - 1));
  bf16x8 o;
#pragma unroll
  for (int j = 0; j < 8; j++)
    o[j] = (__bf16)fmaxf(fmaf((float)v[j], as[colb + j], cs[colb + j]), 0.f);
  *(bf16x8*)(h1b + i * 8) = o;
}

// ====== fused tail: BN2(in-block finalize) + ReLU + residual + head ========
__global__ __launch_bounds__(256) void tail_fused(
    const __bf16* __restrict__ h2b, const __bf16* __restrict__ h1b,
    const float* __restrict__ gstats, const float* __restrict__ g,
    const float* __restrict__ be, const float* __restrict__ w3,
    const float* __restrict__ b3, float* __restrict__ out) {
  __shared__ float w3s[NCLS * NH];
  __shared__ float as[NH], cs[NH];
  for (int i = threadIdx.x; i < NCLS * NH; i += 256) w3s[i] = w3[i];
  {
    const int t = threadIdx.x;
    const float s = gstats[t * 2], ss = gstats[t * 2 + 1];
    const float mean = s * (1.f / 16384.f);
    const float var = ss * (1.f / 16384.f) - mean * mean;
    const float a = g[t] * rsqrtf(var + 1e-5f);
    as[t] = a;
    cs[t] = be[t] - mean * a;
  }
  __syncthreads();

  const int m = blockIdx.x * 256 + threadIdx.x;
  const __bf16* hr = h2b + (size_t)m * NH;
  const __bf16* rr = h1b + (size_t)m * NH;
  float acc[NCLS];
#pragma unroll
  for (int n = 0; n < NCLS; n++) acc[n] = b3[n];

  for (int k = 0; k < NH; k += 8) {
    const bf16x8 hv = *(const bf16x8*)(hr + k);
    const bf16x8 rv = *(const bf16x8*)(rr + k);
    float v[8];
#pragma unroll
    for (int j = 0; j < 8; j++)
      v[j] = fmaxf(fmaf((float)hv[j], as[k + j], cs[k + j]), 0.f) + (float)rv[j];
#pragma unroll
    for (int n = 0; n < NCLS; n++) {
      float d = 0.f;
#pragma unroll
      for (int j = 0; j < 8; j++) d = fmaf(v[j], w3s[n * NH + k + j], d);
      acc[n] += d;
    }
  }

  float mx = acc[0];
#pragma unroll
  for (int n = 1; n < NCLS; n++) mx = fmaxf(mx, acc[n]);
  float se = 0.f;
#pragma unroll
  for (int n = 0; n < NCLS; n++) se += expf(acc[n] - mx);
  const float lse = logf(se) + mx;
#pragma unroll
  for (int n = 0; n < NCLS; n++) out[(size_t)m * NCLS + n] = acc[n] - lse;
}

// =========================== launch ========================================
extern "C" void kernel_launch(void* const* d_in, const int* in_sizes, int n_in,
                              void* d_out, int out_size, void* d_ws, size_t ws_size,
                              hipStream_t stream) {
  const float* x   = (const float*)d_in[0];
  const float* qp  = (const float*)d_in[1];
  const float* w1  = (const float*)d_in[2];
  const float* b1  = (const float*)d_in[3];
  const float* g1  = (const float*)d_in[4];
  const float* be1 = (const float*)d_in[5];
  const float* w2  = (const float*)d_in[6];
  const float* b2  = (const float*)d_in[7];
  const float* g2  = (const float*)d_in[8];
  const float* be2 = (const float*)d_in[9];
  const float* w3  = (const float*)d_in[10];
  const float* b3  = (const float*)d_in[11];
  float* out = (float*)d_out;

  char* w = (char*)d_ws;
  __bf16* h1p   = (__bf16*)w;                         //  8,388,608 (pre-BN1)
  __bf16* h1b   = (__bf16*)(w + 8388608);             //  8,388,608 (post-BN1)
  __bf16* h2b   = (__bf16*)(w + 16777216);            //  8,388,608 (pre-BN2)
  __bf16* w1b   = (__bf16*)(w + 25165824);            //    409,600
  __bf16* w2b   = (__bf16*)(w + 25575424);            //    131,072
  float*  gs1   = (float*)(w + 25706496);             //      2,048
  float*  gs2   = (float*)(w + 25708544);             //      2,048
  __bf16* Abuf  = (__bf16*)(w + 25710592);            //      4,096

  prep_kernel<<<289, 256, 0, stream>>>(qp, w1, w2, Abuf, w1b, w2b, gs1, gs2);

  quanv_fused<<<BQ / 64, 256, 0, stream>>>(x, Abuf, w1b, b1, h1p, gs1);

  bn1_relu<<<(BQ * NH / 8) / 256, 256, 0, stream>>>(h1p, h1b, gs1, g1, be1);

  gemm_bf16_nt<<<(BQ / GBM) * (NH / GBN), 256, 0, stream>>>(
      h1b, w2b, b2, h2b, BQ, NH, NH, gs2);

  tail_fused<<<BQ / 256, 256, 0, stream>>>(h2b, h1b, gs2, g2, be2, w3, b3, out);
}